// Round 4
// baseline (331.208 us; speedup 1.0000x reference)
//
#include <hip/hip_runtime.h>
#include <hip/hip_cooperative_groups.h>
#include <math.h>

namespace cg = cooperative_groups;

#define N 1024
#define E 32
#define L 8
#define NN ((size_t)N * N)

using short8 = __attribute__((ext_vector_type(8))) short;
using f32x4v = __attribute__((ext_vector_type(4))) float;

// split fp32 into bf16 hi + bf16 lo (truncation; residual ~2^-16 relative)
__device__ inline ushort2 split_bf16(float v) {
  unsigned ui = __float_as_uint(v);
  ushort h = (ushort)(ui >> 16);
  float hv = __uint_as_float((unsigned)h << 16);
  float r = v - hv;
  ushort l = (ushort)(__float_as_uint(r) >> 16);
  return make_ushort2(h, l);
}

// async global->LDS, 16B per lane; lds dest = wave-uniform base + lane*16
__device__ inline void gload16(const void* g, void* l) {
  __builtin_amdgcn_global_load_lds(
      (const __attribute__((address_space(1))) unsigned int*)g,
      (__attribute__((address_space(3))) unsigned int*)l, 16, 0, 0);
}

// ---------------- kernel 1: fused wv + P-transpose + tail ----------------
// R1 structure verbatim (measured 80-81 us; left untouched this round as
// the attribution control).
__global__ __launch_bounds__(256) void k_prep(
    const float* __restrict__ feat, const float* __restrict__ fe,
    const float* __restrict__ mono, const float* __restrict__ cm,
    const float* __restrict__ c_i, const float* __restrict__ w_c,
    const float* __restrict__ b_c,
    const float* __restrict__ att_stack, const float* __restrict__ ptr,
    ushort* __restrict__ wv_h, ushort* __restrict__ wv_l,
    ushort* __restrict__ Pt_h, ushort* __restrict__ Pt_l,
    float* __restrict__ out_tail) {
  __shared__ __align__(16) float qsm[32];
  __shared__ ushort Ts[2][64][66];   // pad 66: conflict-free column writes
  int tid = threadIdx.x;
  int b = blockIdx.x;
  if (b < 8192) {
    // ---- wv path (coalesced, 8 lanes/row, 4 rows/thread) ----
    int seg = tid & 7;
    int rl = tid >> 3;             // 0..31 local row
    bool qblock = (b < 8);         // gid < 1024 <=> m == 0
    if (qblock) {                  // compute query cooperatively
      int e = tid >> 3, r = tid & 7;
      float s = 0.f;
      for (int h = r; h < N; h += 8) s += c_i[h] * w_c[e * N + h];
      s += __shfl_down(s, 4, 8);
      s += __shfl_down(s, 2, 8);
      s += __shfl_down(s, 1, 8);
      if (r == 0) qsm[e] = s + b_c[e];
      __syncthreads();
    }
    float4 c = *(const float4*)(cm + seg * 4);
    float4 qa;
    if (qblock) qa = *((const float4*)qsm + seg);
    #pragma unroll
    for (int it = 0; it < 4; ++it) {
      int gid = b * 128 + it * 32 + rl;   // m*N + y
      int m = gid >> 10;
      int y = gid & (N - 1);
      float4 a;
      if (qblock) {
        a = qa;
      } else {
        a = *(const float4*)(feat + ((size_t)(m - 1) * N + y) * E + seg * 4);
      }
      float4 f = *(const float4*)(fe + (size_t)y * E + seg * 4);
      float dx = a.x - f.x, dy = a.y - f.y, dz = a.z - f.z, dw = a.w - f.w;
      float s = c.x * (fmaxf(a.x + f.x, 0.f) - dx * dx)
              + c.y * (fmaxf(a.y + f.y, 0.f) - dy * dy)
              + c.z * (fmaxf(a.z + f.z, 0.f) - dz * dz)
              + c.w * (fmaxf(a.w + f.w, 0.f) - dw * dw);
      s += __shfl_down(s, 4, 8);
      s += __shfl_down(s, 2, 8);
      s += __shfl_down(s, 1, 8);
      if (seg == 0) {
        float v = mono[gid] * s;
        ushort2 hl = split_bf16(v);
        wv_h[gid] = hl.x;
        wv_l[gid] = hl.y;
      }
    }
  } else if (b < 8448) {
    // ---- P-transpose path ----
    int b2 = b - 8192;
    int j0 = (b2 >> 4) * 64;          // k-dim of Pt
    int i0 = (b2 & 15) * 64;          // x-dim of Pt
    float p0 = ptr[0], p1 = ptr[1], p2 = ptr[2], p3 = ptr[3];
    float p4 = ptr[4], p5 = ptr[5], p6 = ptr[6], p7 = ptr[7];
    int w = tid >> 6, lane = tid & 63;
    #pragma unroll 4
    for (int r = 0; r < 16; ++r) {
      int jl = r * 4 + w;
      int il = lane;
      const float4* a =
          (const float4*)(att_stack + ((size_t)(j0 + jl) * N + i0 + il) * L);
      float4 a0 = a[0], a1 = a[1];
      float s = a0.x * p0 + a0.y * p1 + a0.z * p2 + a0.w * p3
              + a1.x * p4 + a1.y * p5 + a1.z * p6 + a1.w * p7;
      ushort2 hl = split_bf16(s);
      Ts[0][il][jl] = hl.x;
      Ts[1][il][jl] = hl.y;
    }
    __syncthreads();
    int il = tid >> 2, cc = tid & 3;
    size_t o = (size_t)(i0 + il) * N + j0 + cc * 16;
    {
      const uint* sp = (const uint*)&Ts[0][il][cc * 16];
      uint4 d0 = {sp[0], sp[1], sp[2], sp[3]};
      uint4 d1 = {sp[4], sp[5], sp[6], sp[7]};
      *(uint4*)&Pt_h[o] = d0;
      *(uint4*)&Pt_h[o + 8] = d1;
    }
    {
      const uint* sp = (const uint*)&Ts[1][il][cc * 16];
      uint4 d0 = {sp[0], sp[1], sp[2], sp[3]};
      uint4 d1 = {sp[4], sp[5], sp[6], sp[7]};
      *(uint4*)&Pt_l[o] = d0;
      *(uint4*)&Pt_l[o + 8] = d1;
    }
  } else {
    // ---- output tail ----
    if (tid < 8) out_tail[tid] = ptr[tid];
    for (int i = tid; i < N; i += 256) out_tail[8 + i] = 0.f;
  }
}

// ---------------- kernel 2: MFMA matmul + grid-sync'd fused blend --------
// Main loop: R1 LDS double-buffered + swizzled version, byte-for-byte
// (best measured). Epilogue: normp -> grid.sync -> norm -> blend from
// in-register acc -> out. C workspace round-trip (8 MB) and the separate
// k_fin launch are eliminated. Cooperative launch: 256 blocks, 69 KB LDS
// -> <=2 blocks/CU -> co-residency guaranteed.
__global__ __launch_bounds__(256) void k_mm(
    const ushort* __restrict__ Pt_h, const ushort* __restrict__ Pt_l,
    const ushort* __restrict__ wv_h, const ushort* __restrict__ wv_l,
    float* __restrict__ normp, const float* __restrict__ att_stack,
    const float* __restrict__ ptr, float* __restrict__ out) {
  __shared__ ushort As[2][2][64][32];   // [buf][plane][row][col]
  __shared__ ushort Bs[2][2][64][32];
  __shared__ float nm[64][17];
  __shared__ float nrm64[64];
  int tid = threadIdx.x;
  int lane = tid & 63, w = tid >> 6;
  int x0 = blockIdx.x * 64, m0 = blockIdx.y * 64;
  int srow = w * 16 + (lane >> 2);
  // swizzled source granule: (lane&3) ^ ((row>>1)&3), row parity = (lane>>3)&3
  int gsrc = (((lane & 3) ^ ((lane >> 3) & 3))) * 8;
  const ushort* gAh = Pt_h + (size_t)(x0 + srow) * N + gsrc;
  const ushort* gAl = Pt_l + (size_t)(x0 + srow) * N + gsrc;
  const ushort* gBh = wv_h + (size_t)(m0 + srow) * N + gsrc;
  const ushort* gBl = wv_l + (size_t)(m0 + srow) * N + gsrc;
  int fr = w * 16 + (lane & 15);
  int fn = lane & 15;
  // physical granule byte offset for ds_read: (gk ^ ((row>>1)&3)) * 16
  int grn = ((lane >> 4) ^ ((lane >> 1) & 3)) << 4;
  f32x4v acc[4];
  #pragma unroll
  for (int t = 0; t < 4; ++t) acc[t] = (f32x4v){0.f, 0.f, 0.f, 0.f};
  // prologue: tile 0 -> buf 0
  gload16(gAh, &As[0][0][w * 16][0]);
  gload16(gAl, &As[0][1][w * 16][0]);
  gload16(gBh, &Bs[0][0][w * 16][0]);
  gload16(gBl, &Bs[0][1][w * 16][0]);
  #pragma unroll 2
  for (int kt = 0; kt < 32; ++kt) {
    int cur = kt & 1;
    __syncthreads();   // drains vmcnt -> buf[cur] ready; buf[cur^1] reads done
    if (kt < 31) {
      int nxt = cur ^ 1;
      gload16(gAh + (kt + 1) * 32, &As[nxt][0][w * 16][0]);
      gload16(gAl + (kt + 1) * 32, &As[nxt][1][w * 16][0]);
      gload16(gBh + (kt + 1) * 32, &Bs[nxt][0][w * 16][0]);
      gload16(gBl + (kt + 1) * 32, &Bs[nxt][1][w * 16][0]);
    }
    const char* aB0 = (const char*)&As[cur][0][0][0];
    const char* aB1 = (const char*)&As[cur][1][0][0];
    short8 Ah = *(const short8*)(aB0 + fr * 64 + grn);
    short8 Al = *(const short8*)(aB1 + fr * 64 + grn);
    const char* bB0 = (const char*)&Bs[cur][0][0][0];
    const char* bB1 = (const char*)&Bs[cur][1][0][0];
    #pragma unroll
    for (int t = 0; t < 4; ++t) {
      short8 Bh = *(const short8*)(bB0 + (t * 16 + fn) * 64 + grn);
      short8 Bl = *(const short8*)(bB1 + (t * 16 + fn) * 64 + grn);
      acc[t] = __builtin_amdgcn_mfma_f32_16x16x32_bf16(Ah, Bh, acc[t], 0, 0, 0);
      acc[t] = __builtin_amdgcn_mfma_f32_16x16x32_bf16(Ah, Bl, acc[t], 0, 0, 0);
      acc[t] = __builtin_amdgcn_mfma_f32_16x16x32_bf16(Al, Bh, acc[t], 0, 0, 0);
    }
  }
  // ---- per-block column max -> normp ----
  // C/D layout: col = lane&15, row = (lane>>4)*4 + reg  [m89-verified]
  int cidx = w * 4 + (lane >> 4);    // 16 contributors per m-column
  #pragma unroll
  for (int t = 0; t < 4; ++t) {
    float mx = fmaxf(fmaxf(acc[t][0], acc[t][1]), fmaxf(acc[t][2], acc[t][3]));
    nm[t * 16 + fn][cidx] = mx;
  }
  __syncthreads();
  if (tid < 64) {
    float mx = nm[tid][0];
    #pragma unroll
    for (int j = 1; j < 16; ++j) mx = fmaxf(mx, nm[tid][j]);
    normp[(size_t)blockIdx.x * N + m0 + tid] = mx;
  }
  // ---- grid-wide barrier: all normp tiles visible ----
  cg::this_grid().sync();
  // ---- finish norm for this block's 64 m-columns ----
  if (tid < 64) {
    int m = m0 + tid;
    float mx = normp[m];
    #pragma unroll
    for (int xg = 1; xg < 16; ++xg)
      mx = fmaxf(mx, normp[(size_t)xg * N + m]);
    nrm64[tid] = (mx <= 1.f) ? 1.f : mx;
  }
  __syncthreads();
  // ---- blend from in-register acc -> out ----
  float p0 = ptr[0], p1 = ptr[1], p2 = ptr[2], p3 = ptr[3];
  float p4 = ptr[4], p5 = ptr[5], p6 = ptr[6], p7 = ptr[7];
  float q0 = 1.f - p0, q1 = 1.f - p1, q2 = 1.f - p2, q3 = 1.f - p3;
  float q4 = 1.f - p4, q5 = 1.f - p5, q6 = 1.f - p6, q7 = 1.f - p7;
  int orow = x0 + w * 16 + (lane >> 4) * 4;
  #pragma unroll
  for (int t = 0; t < 4; ++t) {
    float rn = 1.f / nrm64[t * 16 + fn];
    int ocol = m0 + t * 16 + fn;
    #pragma unroll
    for (int r = 0; r < 4; ++r) {
      float a = acc[t][r] * rn;
      size_t base = ((size_t)(orow + r) * N + ocol) * L;
      const float4* s = (const float4*)(att_stack + base);
      float4 s0 = s[0], s1 = s[1];
      float4 o0, o1;
      o0.x = a * p0 + s0.x * q0;
      o0.y = a * p1 + s0.y * q1;
      o0.z = a * p2 + s0.z * q2;
      o0.w = a * p3 + s0.w * q3;
      o1.x = a * p4 + s1.x * q4;
      o1.y = a * p5 + s1.y * q5;
      o1.z = a * p6 + s1.z * q6;
      o1.w = a * p7 + s1.w * q7;
      float4* o = (float4*)(out + base);
      o[0] = o0;
      o[1] = o1;
    }
  }
}

extern "C" void kernel_launch(void* const* d_in, const int* in_sizes, int n_in,
                              void* d_out, int out_size, void* d_ws, size_t ws_size,
                              hipStream_t stream) {
  const float* feat      = (const float*)d_in[1];
  const float* feat_edge = (const float*)d_in[2];
  const float* c_i       = (const float*)d_in[3];
  const float* att_stack = (const float*)d_in[5];
  const float* stack_ptr = (const float*)d_in[6];
  const float* mono_mask = (const float*)d_in[8];
  const float* cross_mask= (const float*)d_in[9];
  const float* w_c       = (const float*)d_in[10];
  const float* b_c       = (const float*)d_in[11];

  float* out = (float*)d_out;

  // ws layout: 4 ushort planes (8 MB), normp (64 KB)
  ushort* wv_h = (ushort*)d_ws;
  ushort* wv_l = wv_h + NN;
  ushort* Pt_h = wv_l + NN;
  ushort* Pt_l = Pt_h + NN;
  float*  normp= (float*)(Pt_l + NN);  // 16*N

  float* out_tail = out + NN * L;      // stack_ptr + mem zeros

  k_prep<<<8449, 256, 0, stream>>>(feat, feat_edge, mono_mask, cross_mask,
                                   c_i, w_c, b_c, att_stack, stack_ptr,
                                   wv_h, wv_l, Pt_h, Pt_l, out_tail);

  void* args[] = {(void*)&Pt_h, (void*)&Pt_l, (void*)&wv_h, (void*)&wv_l,
                  (void*)&normp, (void*)&att_stack, (void*)&stack_ptr,
                  (void*)&out};
  hipLaunchCooperativeKernel((const void*)k_mm, dim3(16, 16), dim3(256),
                             args, 0, stream);
}

// Round 5
// 279.722 us; speedup vs baseline: 1.1841x; 1.1841x over previous
//
#include <hip/hip_runtime.h>
#include <math.h>

#define N 1024
#define E 32
#define L 8
#define NN ((size_t)N * N)

using short8 = __attribute__((ext_vector_type(8))) short;
using f32x4v = __attribute__((ext_vector_type(4))) float;

// split fp32 into bf16 hi + bf16 lo (truncation; residual ~2^-16 relative)
__device__ inline ushort2 split_bf16(float v) {
  unsigned ui = __float_as_uint(v);
  ushort h = (ushort)(ui >> 16);
  float hv = __uint_as_float((unsigned)h << 16);
  float r = v - hv;
  ushort l = (ushort)(__float_as_uint(r) >> 16);
  return make_ushort2(h, l);
}

// async global->LDS, 16B per lane; lds dest = wave-uniform base + lane*16
__device__ inline void gload16(const void* g, void* l) {
  __builtin_amdgcn_global_load_lds(
      (const __attribute__((address_space(1))) unsigned int*)g,
      (__attribute__((address_space(3))) unsigned int*)l, 16, 0, 0);
}

// ---------------- kernel 1: fused wv + P-transpose + tail ----------------
// blocks [0, 8192): wv path. NEW: feat+fe tiles async-staged to LDS via
//   global_load_lds (8 x 1KB per wave, 32 KB/block in flight) -> compute
//   from LDS. Attacks the measured MLP/latency bound (80 us @ 14% HBM).
// blocks [8192, 8448): Pt[i][j] = att_stack[j,i,:].ptr (transposed, hi/lo)
// block 8448: out tail
__global__ __launch_bounds__(256) void k_prep(
    const float* __restrict__ feat, const float* __restrict__ fe,
    const float* __restrict__ mono, const float* __restrict__ cm,
    const float* __restrict__ c_i, const float* __restrict__ w_c,
    const float* __restrict__ b_c,
    const float* __restrict__ att_stack, const float* __restrict__ ptr,
    ushort* __restrict__ wv_h, ushort* __restrict__ wv_l,
    ushort* __restrict__ Pt_h, ushort* __restrict__ Pt_l,
    float* __restrict__ out_tail) {
  __shared__ __align__(16) float qsm[32];
  __shared__ __align__(16) char smem[32768];   // union: staging / Ts
  int tid = threadIdx.x;
  int b = blockIdx.x;
  if (b < 8192) {
    // ---- wv path: async-staged, then 8 lanes/row, 4 rows/thread ----
    float* Sf = (float*)smem;             // [128][32] feat tile (16 KB)
    float* Se = (float*)(smem + 16384);   // [128][32] fe tile   (16 KB)
    int lane = tid & 63, w = tid >> 6;
    bool qblock = (b < 8);                // gid < 1024 <=> m == 0
    // stage fe tile: y0 = (b*128)&1023 = (b&7)*128, 16 KB contiguous
    {
      const float* fe_t = fe + (size_t)((b & 7) * 128) * E;
      #pragma unroll
      for (int j = 0; j < 4; ++j) {
        int chunk = w * 4 + j;            // 1 KB per chunk
        gload16(fe_t + chunk * 256 + lane * 4, Se + chunk * 256);
      }
    }
    if (!qblock) {
      // stage feat tile: rows gid-1024, 16 KB contiguous
      const float* ft = feat + ((size_t)b * 128 - 1024) * E;
      #pragma unroll
      for (int j = 0; j < 4; ++j) {
        int chunk = w * 4 + j;
        gload16(ft + chunk * 256 + lane * 4, Sf + chunk * 256);
      }
    } else {
      // compute query cooperatively while the fe loads fly
      int e = tid >> 3, r = tid & 7;
      float s = 0.f;
      for (int h = r; h < N; h += 8) s += c_i[h] * w_c[e * N + h];
      s += __shfl_down(s, 4, 8);
      s += __shfl_down(s, 2, 8);
      s += __shfl_down(s, 1, 8);
      if (r == 0) qsm[e] = s + b_c[e];
    }
    __syncthreads();   // drain gloads; qsm visible
    int seg = tid & 7;
    int rl = tid >> 3;             // 0..31 local row
    float4 c = *(const float4*)(cm + seg * 4);
    float4 qa;
    if (qblock) qa = *((const float4*)qsm + seg);
    #pragma unroll
    for (int it = 0; it < 4; ++it) {
      int lr = it * 32 + rl;              // local row 0..127
      int gid = b * 128 + lr;             // m*N + y
      float4 a;
      if (qblock) {
        a = qa;
      } else {
        a = ((const float4*)Sf)[lr * 8 + seg];
      }
      float4 f = ((const float4*)Se)[lr * 8 + seg];
      float dx = a.x - f.x, dy = a.y - f.y, dz = a.z - f.z, dw = a.w - f.w;
      float s = c.x * (fmaxf(a.x + f.x, 0.f) - dx * dx)
              + c.y * (fmaxf(a.y + f.y, 0.f) - dy * dy)
              + c.z * (fmaxf(a.z + f.z, 0.f) - dz * dz)
              + c.w * (fmaxf(a.w + f.w, 0.f) - dw * dw);
      s += __shfl_down(s, 4, 8);
      s += __shfl_down(s, 2, 8);
      s += __shfl_down(s, 1, 8);
      if (seg == 0) {
        float v = mono[gid] * s;
        ushort2 hl = split_bf16(v);
        wv_h[gid] = hl.x;
        wv_l[gid] = hl.y;
      }
    }
  } else if (b < 8448) {
    // ---- P-transpose path (Ts aliased onto smem union) ----
    typedef ushort TsRow[66];
    TsRow* T0 = (TsRow*)smem;        // rows 0..63  (hi plane)
    TsRow* T1 = ((TsRow*)smem) + 64; // rows 64..127 (lo plane)
    int b2 = b - 8192;
    int j0 = (b2 >> 4) * 64;          // k-dim of Pt
    int i0 = (b2 & 15) * 64;          // x-dim of Pt
    float p0 = ptr[0], p1 = ptr[1], p2 = ptr[2], p3 = ptr[3];
    float p4 = ptr[4], p5 = ptr[5], p6 = ptr[6], p7 = ptr[7];
    int w = tid >> 6, lane = tid & 63;
    #pragma unroll 4
    for (int r = 0; r < 16; ++r) {
      int jl = r * 4 + w;
      int il = lane;
      const float4* a =
          (const float4*)(att_stack + ((size_t)(j0 + jl) * N + i0 + il) * L);
      float4 a0 = a[0], a1 = a[1];
      float s = a0.x * p0 + a0.y * p1 + a0.z * p2 + a0.w * p3
              + a1.x * p4 + a1.y * p5 + a1.z * p6 + a1.w * p7;
      ushort2 hl = split_bf16(s);
      T0[il][jl] = hl.x;
      T1[il][jl] = hl.y;
    }
    __syncthreads();
    int il = tid >> 2, cc = tid & 3;
    size_t o = (size_t)(i0 + il) * N + j0 + cc * 16;
    {
      const uint* sp = (const uint*)&T0[il][cc * 16];
      uint4 d0 = {sp[0], sp[1], sp[2], sp[3]};
      uint4 d1 = {sp[4], sp[5], sp[6], sp[7]};
      *(uint4*)&Pt_h[o] = d0;
      *(uint4*)&Pt_h[o + 8] = d1;
    }
    {
      const uint* sp = (const uint*)&T1[il][cc * 16];
      uint4 d0 = {sp[0], sp[1], sp[2], sp[3]};
      uint4 d1 = {sp[4], sp[5], sp[6], sp[7]};
      *(uint4*)&Pt_l[o] = d0;
      *(uint4*)&Pt_l[o + 8] = d1;
    }
  } else {
    // ---- output tail ----
    if (tid < 8) out_tail[tid] = ptr[tid];
    for (int i = tid; i < N; i += 256) out_tail[8 + i] = 0.f;
  }
}

// ---------------- kernel 2: MFMA matmul (R1, best measured) --------------
// C[x,m] = sum_k Pt[x][k] * wv[m][k], bf16 hi/lo (3 products).
// 64x64 tile, BK=32, K=1024; grid (16,16) = 256 blocks.
__global__ __launch_bounds__(256) void k_mm(
    const ushort* __restrict__ Pt_h, const ushort* __restrict__ Pt_l,
    const ushort* __restrict__ wv_h, const ushort* __restrict__ wv_l,
    float* __restrict__ C, float* __restrict__ normp) {
  __shared__ ushort As[2][2][64][32];   // [buf][plane][row][col]
  __shared__ ushort Bs[2][2][64][32];
  __shared__ float nm[64][17];
  int tid = threadIdx.x;
  int lane = tid & 63, w = tid >> 6;
  int x0 = blockIdx.x * 64, m0 = blockIdx.y * 64;
  int srow = w * 16 + (lane >> 2);
  // swizzled source granule: (lane&3) ^ ((row>>1)&3), row parity = (lane>>3)&3
  int gsrc = (((lane & 3) ^ ((lane >> 3) & 3))) * 8;
  const ushort* gAh = Pt_h + (size_t)(x0 + srow) * N + gsrc;
  const ushort* gAl = Pt_l + (size_t)(x0 + srow) * N + gsrc;
  const ushort* gBh = wv_h + (size_t)(m0 + srow) * N + gsrc;
  const ushort* gBl = wv_l + (size_t)(m0 + srow) * N + gsrc;
  int fr = w * 16 + (lane & 15);
  int fn = lane & 15;
  // physical granule byte offset for ds_read: (gk ^ ((row>>1)&3)) * 16
  int grn = ((lane >> 4) ^ ((lane >> 1) & 3)) << 4;
  f32x4v acc[4];
  #pragma unroll
  for (int t = 0; t < 4; ++t) acc[t] = (f32x4v){0.f, 0.f, 0.f, 0.f};
  // prologue: tile 0 -> buf 0
  gload16(gAh, &As[0][0][w * 16][0]);
  gload16(gAl, &As[0][1][w * 16][0]);
  gload16(gBh, &Bs[0][0][w * 16][0]);
  gload16(gBl, &Bs[0][1][w * 16][0]);
  #pragma unroll 2
  for (int kt = 0; kt < 32; ++kt) {
    int cur = kt & 1;
    __syncthreads();   // drains vmcnt -> buf[cur] ready; buf[cur^1] reads done
    if (kt < 31) {
      int nxt = cur ^ 1;
      gload16(gAh + (kt + 1) * 32, &As[nxt][0][w * 16][0]);
      gload16(gAl + (kt + 1) * 32, &As[nxt][1][w * 16][0]);
      gload16(gBh + (kt + 1) * 32, &Bs[nxt][0][w * 16][0]);
      gload16(gBl + (kt + 1) * 32, &Bs[nxt][1][w * 16][0]);
    }
    const char* aB0 = (const char*)&As[cur][0][0][0];
    const char* aB1 = (const char*)&As[cur][1][0][0];
    short8 Ah = *(const short8*)(aB0 + fr * 64 + grn);
    short8 Al = *(const short8*)(aB1 + fr * 64 + grn);
    const char* bB0 = (const char*)&Bs[cur][0][0][0];
    const char* bB1 = (const char*)&Bs[cur][1][0][0];
    #pragma unroll
    for (int t = 0; t < 4; ++t) {
      short8 Bh = *(const short8*)(bB0 + (t * 16 + fn) * 64 + grn);
      short8 Bl = *(const short8*)(bB1 + (t * 16 + fn) * 64 + grn);
      acc[t] = __builtin_amdgcn_mfma_f32_16x16x32_bf16(Ah, Bh, acc[t], 0, 0, 0);
      acc[t] = __builtin_amdgcn_mfma_f32_16x16x32_bf16(Ah, Bl, acc[t], 0, 0, 0);
      acc[t] = __builtin_amdgcn_mfma_f32_16x16x32_bf16(Al, Bh, acc[t], 0, 0, 0);
    }
  }
  // C/D layout: col = lane&15, row = (lane>>4)*4 + reg  [m89-verified]
  int orow = x0 + w * 16 + (lane >> 4) * 4;
  int ocol = m0 + fn;
  int cidx = w * 4 + (lane >> 4);    // 16 contributors per m-column
  #pragma unroll
  for (int t = 0; t < 4; ++t) {
    float mx = -INFINITY;
    #pragma unroll
    for (int r = 0; r < 4; ++r) {
      float v = acc[t][r];
      C[(size_t)(orow + r) * N + ocol + t * 16] = v;
      mx = fmaxf(mx, v);
    }
    nm[t * 16 + fn][cidx] = mx;
  }
  __syncthreads();
  if (tid < 64) {
    float mx = nm[tid][0];
    #pragma unroll
    for (int j = 1; j < 16; ++j) mx = fmaxf(mx, nm[tid][j]);
    normp[(size_t)blockIdx.x * N + m0 + tid] = mx;
  }
}

// ---------------- kernel 3: fused norm-finish + blend (R1) ---------------
__global__ __launch_bounds__(256) void k_fin(
    const float* __restrict__ C, const float* __restrict__ normp,
    const float* __restrict__ att_stack, const float* __restrict__ ptr,
    float* __restrict__ out) {
  int gid = blockIdx.x * 256 + threadIdx.x;   // x*N + m
  int m = gid & (N - 1);
  float mx = normp[m];
  #pragma unroll
  for (int xg = 1; xg < 16; ++xg)
    mx = fmaxf(mx, normp[(size_t)xg * N + m]);
  float nrm = (mx <= 1.f) ? 1.f : mx;
  float a = C[gid] / nrm;
  const float4* s = (const float4*)(att_stack + (size_t)gid * L);
  float4 s0 = s[0], s1 = s[1];
  float p0 = ptr[0], p1 = ptr[1], p2 = ptr[2], p3 = ptr[3];
  float p4 = ptr[4], p5 = ptr[5], p6 = ptr[6], p7 = ptr[7];
  float4 o0, o1;
  o0.x = a * p0 + s0.x * (1.f - p0);
  o0.y = a * p1 + s0.y * (1.f - p1);
  o0.z = a * p2 + s0.z * (1.f - p2);
  o0.w = a * p3 + s0.w * (1.f - p3);
  o1.x = a * p4 + s1.x * (1.f - p4);
  o1.y = a * p5 + s1.y * (1.f - p5);
  o1.z = a * p6 + s1.z * (1.f - p6);
  o1.w = a * p7 + s1.w * (1.f - p7);
  float4* o = (float4*)(out + (size_t)gid * L);
  o[0] = o0;
  o[1] = o1;
}

extern "C" void kernel_launch(void* const* d_in, const int* in_sizes, int n_in,
                              void* d_out, int out_size, void* d_ws, size_t ws_size,
                              hipStream_t stream) {
  const float* feat      = (const float*)d_in[1];
  const float* feat_edge = (const float*)d_in[2];
  const float* c_i       = (const float*)d_in[3];
  const float* att_stack = (const float*)d_in[5];
  const float* stack_ptr = (const float*)d_in[6];
  const float* mono_mask = (const float*)d_in[8];
  const float* cross_mask= (const float*)d_in[9];
  const float* w_c       = (const float*)d_in[10];
  const float* b_c       = (const float*)d_in[11];

  float* out = (float*)d_out;

  // ws layout: 4 ushort planes (8 MB), C (4 MB), normp (64 KB)
  ushort* wv_h = (ushort*)d_ws;
  ushort* wv_l = wv_h + NN;
  ushort* Pt_h = wv_l + NN;
  ushort* Pt_l = Pt_h + NN;
  float*  C    = (float*)(Pt_l + NN);
  float*  normp= C + NN;               // 16*N

  float* out_tail = out + NN * L;      // stack_ptr + mem zeros

  k_prep<<<8449, 256, 0, stream>>>(feat, feat_edge, mono_mask, cross_mask,
                                   c_i, w_c, b_c, att_stack, stack_ptr,
                                   wv_h, wv_l, Pt_h, Pt_l, out_tail);
  dim3 mmgrid(16, 16);
  k_mm<<<mmgrid, 256, 0, stream>>>(Pt_h, Pt_l, wv_h, wv_l, C, normp);
  k_fin<<<4096, 256, 0, stream>>>(C, normp, att_stack, stack_ptr, out);
}

// Round 6
// 275.231 us; speedup vs baseline: 1.2034x; 1.0163x over previous
//
#include <hip/hip_runtime.h>
#include <math.h>

#define N 1024
#define E 32
#define L 8
#define NN ((size_t)N * N)

using short8 = __attribute__((ext_vector_type(8))) short;
using f32x4v = __attribute__((ext_vector_type(4))) float;

// fp32 -> bf16 round-to-nearest-even
__device__ inline ushort bf16_rtne(float v) {
  unsigned u = __float_as_uint(v);
  return (ushort)((u + 0x7FFF + ((u >> 16) & 1)) >> 16);
}

// async global->LDS, 16B per lane; lds dest = wave-uniform base + lane*16
__device__ inline void gload16(const void* g, void* l) {
  __builtin_amdgcn_global_load_lds(
      (const __attribute__((address_space(1))) unsigned int*)g,
      (__attribute__((address_space(3))) unsigned int*)l, 16, 0, 0);
}

// ---------------- kernel 1: fused wv + P-transpose + tail ----------------
// R1 structure (best measured), single bf16 plane (RTNE).
// blocks [0, 8192): wv[m,y] = mono*sum_e cm[e]*(-(I-fe)^2+relu(I+fe))
// blocks [8192, 8448): Pt[i][j] = att_stack[j,i,:].ptr (transposed)
// block 8448: out tail
__global__ __launch_bounds__(256) void k_prep(
    const float* __restrict__ feat, const float* __restrict__ fe,
    const float* __restrict__ mono, const float* __restrict__ cm,
    const float* __restrict__ c_i, const float* __restrict__ w_c,
    const float* __restrict__ b_c,
    const float* __restrict__ att_stack, const float* __restrict__ ptr,
    ushort* __restrict__ wv, ushort* __restrict__ Pt,
    float* __restrict__ out_tail) {
  __shared__ __align__(16) float qsm[32];
  __shared__ ushort Ts[64][66];   // pad 66: conflict-free column writes
  int tid = threadIdx.x;
  int b = blockIdx.x;
  if (b < 8192) {
    // ---- wv path (coalesced, 8 lanes/row, 4 rows/thread) ----
    int seg = tid & 7;
    int rl = tid >> 3;             // 0..31 local row
    bool qblock = (b < 8);         // gid < 1024 <=> m == 0
    if (qblock) {                  // compute query cooperatively
      int e = tid >> 3, r = tid & 7;
      float s = 0.f;
      for (int h = r; h < N; h += 8) s += c_i[h] * w_c[e * N + h];
      s += __shfl_down(s, 4, 8);
      s += __shfl_down(s, 2, 8);
      s += __shfl_down(s, 1, 8);
      if (r == 0) qsm[e] = s + b_c[e];
      __syncthreads();
    }
    float4 c = *(const float4*)(cm + seg * 4);
    float4 qa;
    if (qblock) qa = *((const float4*)qsm + seg);
    #pragma unroll
    for (int it = 0; it < 4; ++it) {
      int gid = b * 128 + it * 32 + rl;   // m*N + y
      int m = gid >> 10;
      int y = gid & (N - 1);
      float4 a;
      if (qblock) {
        a = qa;
      } else {
        a = *(const float4*)(feat + ((size_t)(m - 1) * N + y) * E + seg * 4);
      }
      float4 f = *(const float4*)(fe + (size_t)y * E + seg * 4);
      float dx = a.x - f.x, dy = a.y - f.y, dz = a.z - f.z, dw = a.w - f.w;
      float s = c.x * (fmaxf(a.x + f.x, 0.f) - dx * dx)
              + c.y * (fmaxf(a.y + f.y, 0.f) - dy * dy)
              + c.z * (fmaxf(a.z + f.z, 0.f) - dz * dz)
              + c.w * (fmaxf(a.w + f.w, 0.f) - dw * dw);
      s += __shfl_down(s, 4, 8);
      s += __shfl_down(s, 2, 8);
      s += __shfl_down(s, 1, 8);
      if (seg == 0) {
        wv[gid] = bf16_rtne(mono[gid] * s);
      }
    }
  } else if (b < 8448) {
    // ---- P-transpose path ----
    int b2 = b - 8192;
    int j0 = (b2 >> 4) * 64;          // k-dim of Pt
    int i0 = (b2 & 15) * 64;          // x-dim of Pt
    float p0 = ptr[0], p1 = ptr[1], p2 = ptr[2], p3 = ptr[3];
    float p4 = ptr[4], p5 = ptr[5], p6 = ptr[6], p7 = ptr[7];
    int w = tid >> 6, lane = tid & 63;
    #pragma unroll 4
    for (int r = 0; r < 16; ++r) {
      int jl = r * 4 + w;
      int il = lane;
      const float4* a =
          (const float4*)(att_stack + ((size_t)(j0 + jl) * N + i0 + il) * L);
      float4 a0 = a[0], a1 = a[1];
      float s = a0.x * p0 + a0.y * p1 + a0.z * p2 + a0.w * p3
              + a1.x * p4 + a1.y * p5 + a1.z * p6 + a1.w * p7;
      Ts[il][jl] = bf16_rtne(s);
    }
    __syncthreads();
    int il = tid >> 2, cc = tid & 3;
    size_t o = (size_t)(i0 + il) * N + j0 + cc * 16;
    const uint* sp = (const uint*)&Ts[il][cc * 16];
    uint4 d0 = {sp[0], sp[1], sp[2], sp[3]};
    uint4 d1 = {sp[4], sp[5], sp[6], sp[7]};
    *(uint4*)&Pt[o] = d0;
    *(uint4*)&Pt[o + 8] = d1;
  } else {
    // ---- output tail ----
    if (tid < 8) out_tail[tid] = ptr[tid];
    for (int i = tid; i < N; i += 256) out_tail[8 + i] = 0.f;
  }
}

// ---------------- kernel 2: MFMA matmul, 32x32 tiles, 4 blocks/CU --------
// C[x,m] = sum_k Pt[x][k] * wv[m][k], single bf16 product.
// Grid (32,32) = 1024 blocks = 4/CU (vs old 1/CU): barrier stalls overlap
// across resident blocks. Per wave: one 16x16 quadrant, 1 MFMA/K-step.
// Staging: 1 gload16/thread/K-step; same verified XOR granule swizzle
// (LDS[row][g] = global[row][g ^ ((row&15)>>1 & 3)], applied on the global
// source address; read side XORs identically). Single barrier per K-step,
// double-buffered. wv+Pt are 2 MB each -> fully L2-resident per XCD.
__global__ __launch_bounds__(256) void k_mm(
    const ushort* __restrict__ Pt, const ushort* __restrict__ wv,
    float* __restrict__ C, float* __restrict__ normp) {
  __shared__ ushort As[2][32][32];   // [buf][row][col]
  __shared__ ushort Bs[2][32][32];
  __shared__ float nm[32][9];
  int tid = threadIdx.x;
  int lane = tid & 63, w = tid >> 6;
  int x0 = blockIdx.x * 32, m0 = blockIdx.y * 32;
  // staging: waves 0,1 -> As rows (w&1)*16+.. ; waves 2,3 -> Bs
  int srow = (w & 1) * 16 + (lane >> 2);
  int gsrc = ((lane & 3) ^ ((lane >> 3) & 3)) * 8;   // pre-swizzled source
  const ushort* gp = (w < 2) ? Pt + (size_t)(x0 + srow) * N + gsrc
                             : wv + (size_t)(m0 + srow) * N + gsrc;
  // read side: wave quadrant (wr, wc)
  int wr = w >> 1, wc = w & 1;
  int fr = lane & 15;
  int grn = ((lane >> 4) ^ ((fr >> 1) & 3)) << 4;    // phys granule byte off
  const char* aBase = (const char*)&As[0][0][0];
  const char* bBase = (const char*)&Bs[0][0][0];
  int aOff = (wr * 16 + fr) * 64 + grn;
  int bOff = (wc * 16 + fr) * 64 + grn;
  f32x4v acc = (f32x4v){0.f, 0.f, 0.f, 0.f};
  // prologue: K-step 0 -> buf 0
  {
    ushort* dst = (w < 2) ? &As[0][(w & 1) * 16][0] : &Bs[0][(w & 1) * 16][0];
    gload16(gp, dst);
  }
  #pragma unroll 2
  for (int kt = 0; kt < 32; ++kt) {
    int cur = kt & 1;
    __syncthreads();   // drains vmcnt -> buf[cur] ready; buf[cur^1] read done
    if (kt < 31) {
      int nxt = cur ^ 1;
      ushort* dst = (w < 2) ? &As[nxt][(w & 1) * 16][0]
                            : &Bs[nxt][(w & 1) * 16][0];
      gload16(gp + (kt + 1) * 32, dst);
    }
    short8 Av = *(const short8*)(aBase + cur * 2048 + aOff);
    short8 Bv = *(const short8*)(bBase + cur * 2048 + bOff);
    acc = __builtin_amdgcn_mfma_f32_16x16x32_bf16(Av, Bv, acc, 0, 0, 0);
  }
  // C/D layout: col = lane&15, row = (lane>>4)*4 + reg  [m89-verified]
  int orow = x0 + wr * 16 + (lane >> 4) * 4;
  int ocol = m0 + wc * 16 + fr;
  float mx = -INFINITY;
  #pragma unroll
  for (int r = 0; r < 4; ++r) {
    float v = acc[r];
    C[(size_t)(orow + r) * N + ocol] = v;
    mx = fmaxf(mx, v);
  }
  nm[wc * 16 + fr][wr * 4 + (lane >> 4)] = mx;   // 8 contributors/column
  __syncthreads();
  if (tid < 32) {
    float m2 = nm[tid][0];
    #pragma unroll
    for (int j = 1; j < 8; ++j) m2 = fmaxf(m2, nm[tid][j]);
    normp[(size_t)blockIdx.x * N + m0 + tid] = m2;
  }
}

// ---------------- kernel 3: fused norm-finish + blend --------------------
// norm[m] = max over 32 x-tiles of normp (128 KB, L2-resident).
__global__ __launch_bounds__(256) void k_fin(
    const float* __restrict__ C, const float* __restrict__ normp,
    const float* __restrict__ att_stack, const float* __restrict__ ptr,
    float* __restrict__ out) {
  int gid = blockIdx.x * 256 + threadIdx.x;   // x*N + m
  int m = gid & (N - 1);
  float mx = normp[m];
  #pragma unroll
  for (int xg = 1; xg < 32; ++xg)
    mx = fmaxf(mx, normp[(size_t)xg * N + m]);
  float nrm = (mx <= 1.f) ? 1.f : mx;
  float a = C[gid] / nrm;
  const float4* s = (const float4*)(att_stack + (size_t)gid * L);
  float4 s0 = s[0], s1 = s[1];
  float p0 = ptr[0], p1 = ptr[1], p2 = ptr[2], p3 = ptr[3];
  float p4 = ptr[4], p5 = ptr[5], p6 = ptr[6], p7 = ptr[7];
  float4 o0, o1;
  o0.x = a * p0 + s0.x * (1.f - p0);
  o0.y = a * p1 + s0.y * (1.f - p1);
  o0.z = a * p2 + s0.z * (1.f - p2);
  o0.w = a * p3 + s0.w * (1.f - p3);
  o1.x = a * p4 + s1.x * (1.f - p4);
  o1.y = a * p5 + s1.y * (1.f - p5);
  o1.z = a * p6 + s1.z * (1.f - p6);
  o1.w = a * p7 + s1.w * (1.f - p7);
  float4* o = (float4*)(out + (size_t)gid * L);
  o[0] = o0;
  o[1] = o1;
}

extern "C" void kernel_launch(void* const* d_in, const int* in_sizes, int n_in,
                              void* d_out, int out_size, void* d_ws, size_t ws_size,
                              hipStream_t stream) {
  const float* feat      = (const float*)d_in[1];
  const float* feat_edge = (const float*)d_in[2];
  const float* c_i       = (const float*)d_in[3];
  const float* att_stack = (const float*)d_in[5];
  const float* stack_ptr = (const float*)d_in[6];
  const float* mono_mask = (const float*)d_in[8];
  const float* cross_mask= (const float*)d_in[9];
  const float* w_c       = (const float*)d_in[10];
  const float* b_c       = (const float*)d_in[11];

  float* out = (float*)d_out;

  // ws layout: wv (2 MB), Pt (2 MB), C (4 MB), normp (128 KB)
  ushort* wv   = (ushort*)d_ws;
  ushort* Pt   = wv + NN;
  float*  C    = (float*)(Pt + NN);
  float*  normp= C + NN;               // 32*N

  float* out_tail = out + NN * L;      // stack_ptr + mem zeros

  k_prep<<<8449, 256, 0, stream>>>(feat, feat_edge, mono_mask, cross_mask,
                                   c_i, w_c, b_c, att_stack, stack_ptr,
                                   wv, Pt, out_tail);
  dim3 mmgrid(32, 32);
  k_mm<<<mmgrid, 256, 0, stream>>>(Pt, wv, C, normp);
  k_fin<<<4096, 256, 0, stream>>>(C, normp, att_stack, stack_ptr, out);
}